// Round 14
// baseline (177.469 us; speedup 1.0000x reference)
//
#include <hip/hip_runtime.h>
#include <hip/hip_bf16.h>

#define NN 4096
#define DD 128
#define NS 75
#define TOT (NN * NN)

// k_d2 tiling (MFMA): 128x128 block, 4 waves, 64x64 per wave
#define BT 128
#define NBD2 (NN / BT)                      // 32
#define GRID_D2 (NBD2 * (NBD2 + 1) / 2)     // 528

// sweep tiling: 64x64 tiles, 256 threads, 16 elems/thread (register-resident)
#define SB 64
#define NBSW (NN / SB)                      // 64
#define GRID_SW (NBSW * (NBSW + 1) / 2)     // 2080

typedef float v2f __attribute__((ext_vector_type(2)));
typedef float f32x4 __attribute__((ext_vector_type(4)));
typedef short bf16x8 __attribute__((ext_vector_type(8)));

__device__ __forceinline__ float fexp2(float v) { return __builtin_amdgcn_exp2f(v); }

// DPP lane-shift add: no LDS/ds_bpermute latency (register-file crossing, ~2cy).
template <int CTRL>
__device__ __forceinline__ float dpp_add(float x) {
    int y = __builtin_amdgcn_update_dpp(0, __float_as_int(x), CTRL, 0xf, 0xf, true);
    return x + __int_as_float(y);
}
// Full wave64 sum; result lands in lane 63. Canonical gfx9 sequence.
__device__ __forceinline__ float wave_sum(float x) {
    x = dpp_add<0x111>(x);   // row_shr:1
    x = dpp_add<0x112>(x);   // row_shr:2
    x = dpp_add<0x114>(x);   // row_shr:4
    x = dpp_add<0x118>(x);   // row_shr:8  -> lane15 of each row16 = row sum
    x = dpp_add<0x142>(x);   // row_bcast:15
    x = dpp_add<0x143>(x);   // row_bcast:31 -> lane63 = wave sum
    return x;
}

// linear index -> (bi, bj) with bi <= bj, row-major over upper triangle
__device__ __forceinline__ void tri_decode(int t, int nb, int& bi, int& bj) {
    int b = 0, rem = t;
    while (rem >= nb - b) { rem -= nb - b; ++b; }   // uniform across block -> scalar
    bi = b; bj = b + rem;
}

// Split f32 -> bf16 hi (bit-truncate, top 16 bits) + bf16 lo (truncate of exact
// residual). x ~= hi + lo with |err| <= 2^-14 |x|; G error << d2 tolerance.
__device__ __forceinline__ void cvt_split(const float4& v0, const float4& v1,
                                          bf16x8& hi, bf16x8& lo) {
    float f[8] = {v0.x, v0.y, v0.z, v0.w, v1.x, v1.y, v1.z, v1.w};
#pragma unroll
    for (int j = 0; j < 8; ++j) {
        unsigned b = __float_as_uint(f[j]);
        hi[j] = (short)(b >> 16);
        float l = f[j] - __uint_as_float(b & 0xFFFF0000u);   // exact residual
        lo[j] = (short)(__float_as_uint(l) >> 16);
    }
}

// Coarse window logic (deterministic; recomputed per consumer block).
// Peak of unimodal curve sampled at stride 3 -> window [3*bk-2, 3*bk+2] clamp.
__device__ __forceinline__ int coarse_window(const double* KL, const double* KK) {
    double best = -1.0;
    int bk = 0;
    for (int k = 0; k < 25; ++k) {
        double loss = KL[k] / sqrt(KK[k]);
        if (loss > best) { best = loss; bk = k; }   // strict > = first max
    }
    int wv = 3 * bk - 2;
    if (wv < 0) wv = 0;
    if (wv > NS - 5) wv = NS - 5;
    return wv;
}

// ---------------- ws layout (bytes) ----------------
#define WS_DSUM 0                      // double
#define WS_NZC  8                      // unsigned long long
#define WS_KL   16                     // double[32]  (0..24 coarse, 25..29 refine)
#define WS_KK   (16 + 256)             // double[32]
#define WS_SQ   (16 + 512)             // float[NN]
#define WS_CSIG (WS_SQ + 4 * NN)       // float[NS]

__global__ void k_rowsq(const float* __restrict__ x, float* __restrict__ sq,
                        double* __restrict__ dsum, unsigned long long* __restrict__ nzc) {
    int tid = blockIdx.x * blockDim.x + threadIdx.x;
    if (tid == 0) { *dsum = 0.0; *nzc = 0ull; }
    if (tid < NN) {
        const float4* row = (const float4*)(x + (size_t)tid * DD);
        float s = 0.f;
#pragma unroll
        for (int i = 0; i < DD / 4; ++i) {
            float4 v = row[i];
            s += v.x * v.x + v.y * v.y + v.z * v.z + v.w * v.w;
        }
        sq[tid] = s;
    }
}

// d2 via split-bf16 MFMA: G = hi.hi^T + hi.lo^T + lo.hi^T (lo.lo dropped).
__launch_bounds__(256)
__global__ void k_d2(const float* __restrict__ x, const float* __restrict__ sq,
                     float* __restrict__ d2, double* __restrict__ dsum,
                     unsigned long long* __restrict__ nzc) {
    __shared__ double red_d[4];
    __shared__ int red_n[4];

    int bi, bj;
    tri_decode(blockIdx.x, NBD2, bi, bj);
    const int r0 = bi * BT, c0 = bj * BT;
    const int tid = threadIdx.x;
    const int l  = tid & 63, wid = tid >> 6;
    const int wr = wid >> 1, wc = wid & 1;    // wave tile: 64x64
    const int lr = l & 15;
    const int lk = (l >> 4) * 8;
    const int l4 = (l >> 4) * 4;

    const int ar = r0 + wr * 64 + lr;
    const int br = c0 + wc * 64 + lr;

    f32x4 acc[4][4];
#pragma unroll
    for (int a = 0; a < 4; ++a)
#pragma unroll
        for (int b = 0; b < 4; ++b) acc[a][b] = (f32x4){0.f, 0.f, 0.f, 0.f};

#pragma unroll 1
    for (int kc = 0; kc < 4; ++kc) {
        const int k0 = kc * 32 + lk;
        bf16x8 ah[4], al[4], bh[4], bl[4];
#pragma unroll
        for (int t = 0; t < 4; ++t) {
            const float* pa = x + (size_t)(ar + t * 16) * DD + k0;
            float4 a0 = *(const float4*)pa;
            float4 a1 = *(const float4*)(pa + 4);
            cvt_split(a0, a1, ah[t], al[t]);
            const float* pb = x + (size_t)(br + t * 16) * DD + k0;
            float4 b0 = *(const float4*)pb;
            float4 b1 = *(const float4*)(pb + 4);
            cvt_split(b0, b1, bh[t], bl[t]);
        }
#pragma unroll
        for (int a = 0; a < 4; ++a)
#pragma unroll
            for (int b = 0; b < 4; ++b) {
                acc[a][b] = __builtin_amdgcn_mfma_f32_16x16x32_bf16(ah[a], bh[b], acc[a][b], 0, 0, 0);
                acc[a][b] = __builtin_amdgcn_mfma_f32_16x16x32_bf16(ah[a], bl[b], acc[a][b], 0, 0, 0);
                acc[a][b] = __builtin_amdgcn_mfma_f32_16x16x32_bf16(al[a], bh[b], acc[a][b], 0, 0, 0);
            }
    }

    float myd = 0.f;
    int myn = 0;
#pragma unroll
    for (int a = 0; a < 4; ++a) {
        const int grb = r0 + wr * 64 + a * 16 + l4;
        float4 sqr = *(const float4*)(sq + grb);
        float sr[4] = {sqr.x, sqr.y, sqr.z, sqr.w};
#pragma unroll
        for (int b = 0; b < 4; ++b) {
            const int gc = c0 + wc * 64 + b * 16 + lr;
            const float sc = sq[gc];
            float dv[4];
#pragma unroll
            for (int v = 0; v < 4; ++v) {
                float d = fmaxf(sr[v] + sc - 2.f * acc[a][b][v], 0.f);
                dv[v] = d;
                if (d > 0.f) { myd += sqrtf(d); ++myn; }
                d2[(size_t)(grb + v) * NN + gc] = d;
            }
            if (bi != bj) {
                float4 o = {dv[0], dv[1], dv[2], dv[3]};
                *(float4*)(d2 + (size_t)gc * NN + grb) = o;
            }
        }
    }

    const int w = (bi == bj) ? 1 : 2;
    float sd = wave_sum(myd);
    float sn = wave_sum((float)myn);
    if ((tid & 63) == 63) { red_d[wid] = (double)sd; red_n[wid] = (int)sn; }
    __syncthreads();
    if (tid == 0) {
        double td = red_d[0] + red_d[1] + red_d[2] + red_d[3];
        int tn = red_n[0] + red_n[1] + red_n[2] + red_n[3];
        atomicAdd(dsum, td * (double)w);
        atomicAdd(nzc, (unsigned long long)(tn * w));
    }
}

__global__ void k_sigmas(const double* __restrict__ dsum, const unsigned long long* __restrict__ nzc,
                         float* __restrict__ csig, double* __restrict__ KL, double* __restrict__ KK) {
    int t = threadIdx.x;
    float mean = (float)(*dsum / (double)(*nzc));
    float lo = 0.1f * mean;
    float hi = 10.0f * mean;
    float step = (hi - lo) / (float)NS;
    if (t < NS) {
        float s = lo + step * (float)t;
        csig[t] = (float)(1.4426950408889634 / ((double)s * (double)s));
    }
    if (t < 32) { KL[t] = 0.0; KK[t] = 0.0; }
}

// One sigma-phase over register-resident data: CH sigmas at csig indices
// STRIDE*(S0+s)+OFF, partials into part[wave][S0+s] (kl) / [25-ish+S0+s] (kk).
template <int CH, int S0, int STRIDE, int NSLOT>
__device__ __forceinline__ void sweep_phase(const v2f* nd, const v2f* ll,
                                            const float* __restrict__ csig, int off,
                                            double part[4][2 * NSLOT],
                                            int wave, int lane, float w) {
    float c[CH];
#pragma unroll
    for (int s = 0; s < CH; ++s)   // force SGPR residency
        c[s] = __int_as_float(__builtin_amdgcn_readfirstlane(
                   __float_as_int(csig[off + STRIDE * (S0 + s)])));
    v2f akl[CH], akk[CH];
#pragma unroll
    for (int s = 0; s < CH; ++s) { akl[s] = (v2f){0.f, 0.f}; akk[s] = (v2f){0.f, 0.f}; }

#pragma unroll
    for (int e = 0; e < 8; ++e) {
        v2f ndv = nd[e], L = ll[e];
#pragma unroll
        for (int s = 0; s < CH; ++s) {
            v2f arg = ndv * c[s];                               // v_pk_mul_f32
            v2f K = {fexp2(arg.x), fexp2(arg.y)};               // 2x v_exp_f32
            akl[s] = __builtin_elementwise_fma(K, L, akl[s]);   // v_pk_fma_f32
            akk[s] = __builtin_elementwise_fma(K, K, akk[s]);
        }
    }

#pragma unroll
    for (int s = 0; s < CH; ++s) {
        float v1 = wave_sum(akl[s].x + akl[s].y);   // DPP: result in lane 63
        float v2 = wave_sum(akk[s].x + akk[s].y);
        if (lane == 63) {
            part[wave][S0 + s]         = (double)(v1 * w);
            part[wave][NSLOT + S0 + s] = (double)(v2 * w);
        }
    }
}

__device__ __forceinline__ void sweep_load(const float* __restrict__ d2,
                                           const float* __restrict__ lk,
                                           int r0, int c0, v2f* nd, v2f* ll) {
    const int rr = threadIdx.x >> 4;
    const int c4 = (threadIdx.x & 15) * 4;
#pragma unroll
    for (int it = 0; it < 4; ++it) {
        size_t off = (size_t)(r0 + rr + 16 * it) * NN + c0 + c4;
        float4 dv = *(const float4*)(d2 + off);
        float4 lv = *(const float4*)(lk + off);
        nd[it * 2 + 0] = (v2f){-dv.x, -dv.y};
        nd[it * 2 + 1] = (v2f){-dv.z, -dv.w};
        ll[it * 2 + 0] = (v2f){lv.x, lv.y};
        ll[it * 2 + 1] = (v2f){lv.z, lv.w};
    }
}

// Coarse: 25 sigmas (stride 3) in two wide phases CH=13 + CH=12 (R11 geometry:
// wide chunks amortize data regs + reduction; 60->~38us vs R13's CH=5x5).
__launch_bounds__(256, 3)
__global__ void k_sweep_coarse(const float* __restrict__ d2, const float* __restrict__ lk,
                               const float* __restrict__ csig, double* __restrict__ KL,
                               double* __restrict__ KK) {
    int bi, bj;
    tri_decode(blockIdx.x, NBSW, bi, bj);
    const int r0 = bi * SB, c0 = bj * SB;
    const float w = (bi == bj) ? 1.f : 2.f;

    v2f nd[8], ll[8];
    sweep_load(d2, lk, r0, c0, nd, ll);

    __shared__ double part[4][50];
    const int lane = threadIdx.x & 63, wave = threadIdx.x >> 6;

    sweep_phase<13, 0, 3, 25>(nd, ll, csig, 0, part, wave, lane, w);
    sweep_phase<12, 13, 3, 25>(nd, ll, csig, 0, part, wave, lane, w);

    __syncthreads();
    const int t = threadIdx.x;
    if (t < 50) {
        double v = part[0][t] + part[1][t] + part[2][t] + part[3][t];
        if (t < 25) atomicAdd(&KL[t], v);
        else        atomicAdd(&KK[t - 25], v);
    }
}

// Refine: each block recomputes the coarse window (deterministic), evaluates
// 5 stride-1 sigmas at w0.., accumulates into slots 25..29.
__launch_bounds__(256, 3)
__global__ void k_sweep_refine(const float* __restrict__ d2, const float* __restrict__ lk,
                               const float* __restrict__ csig, double* __restrict__ KL,
                               double* __restrict__ KK) {
    __shared__ int w0_sh;
    if (threadIdx.x == 0) w0_sh = coarse_window(KL, KK);
    __syncthreads();
    const int s0 = w0_sh;

    int bi, bj;
    tri_decode(blockIdx.x, NBSW, bi, bj);
    const int r0 = bi * SB, c0 = bj * SB;
    const float w = (bi == bj) ? 1.f : 2.f;

    v2f nd[8], ll[8];
    sweep_load(d2, lk, r0, c0, nd, ll);

    __shared__ double part[4][10];
    const int lane = threadIdx.x & 63, wave = threadIdx.x >> 6;

    sweep_phase<5, 0, 1, 5>(nd, ll, csig, s0, part, wave, lane, w);

    __syncthreads();
    const int t = threadIdx.x;
    if (t < 10) {
        double v = part[0][t] + part[1][t] + part[2][t] + part[3][t];
        if (t < 5) atomicAdd(&KL[25 + t], v);
        else       atomicAdd(&KK[25 + t - 5], v);
    }
}

// Final: recompute copt per block (coarse window + refine argmax), then
// A = exp2(-d2*c)/n over upper-tri blocks with mirror writes.
__launch_bounds__(256)
__global__ void k_final(float* __restrict__ d2, const double* __restrict__ KL,
                        const double* __restrict__ KK, const float* __restrict__ csig) {
    __shared__ float cc_sh;
    if (threadIdx.x == 0) {
        int wv = coarse_window(KL, KK);
        double best = -1.0;
        int bk = 0;
        for (int k = 0; k < 5; ++k) {
            double loss = KL[25 + k] / sqrt(KK[25 + k]);
            if (loss > best) { best = loss; bk = k; }   // strict > = first max
        }
        cc_sh = csig[wv + bk];
    }
    __syncthreads();
    const float cc = cc_sh;
    const float inv_n = 1.0f / (float)NN;

    int bi, bj;
    tri_decode(blockIdx.x, NBD2, bi, bj);
    const int r0 = bi * BT, c0 = bj * BT;
    const int tx = threadIdx.x & 31, ty = threadIdx.x >> 5;

    float a[16][4];
#pragma unroll
    for (int r = 0; r < 16; ++r) {
        size_t off = (size_t)(r0 + ty * 16 + r) * NN + c0 + tx * 4;
        float4 v = *(const float4*)(d2 + off);
        a[r][0] = fexp2(-v.x * cc) * inv_n;
        a[r][1] = fexp2(-v.y * cc) * inv_n;
        a[r][2] = fexp2(-v.z * cc) * inv_n;
        a[r][3] = fexp2(-v.w * cc) * inv_n;
        float4 o = {a[r][0], a[r][1], a[r][2], a[r][3]};
        *(float4*)(d2 + off) = o;
    }
    if (bi != bj) {
#pragma unroll
        for (int c = 0; c < 4; ++c) {
            size_t base = (size_t)(c0 + tx * 4 + c) * NN + r0 + ty * 16;
            float4 w0 = {a[0][c],  a[1][c],  a[2][c],  a[3][c]};
            float4 w1 = {a[4][c],  a[5][c],  a[6][c],  a[7][c]};
            float4 w2 = {a[8][c],  a[9][c],  a[10][c], a[11][c]};
            float4 w3 = {a[12][c], a[13][c], a[14][c], a[15][c]};
            *(float4*)(d2 + base + 0)  = w0;
            *(float4*)(d2 + base + 4)  = w1;
            *(float4*)(d2 + base + 8)  = w2;
            *(float4*)(d2 + base + 12) = w3;
        }
    }
}

extern "C" void kernel_launch(void* const* d_in, const int* in_sizes, int n_in,
                              void* d_out, int out_size, void* d_ws, size_t ws_size,
                              hipStream_t stream) {
    const float* x  = (const float*)d_in[0];
    const float* lk = (const float*)d_in[1];
    float* out = (float*)d_out;   // doubles as the d2 buffer, transformed in place at the end
    char* ws = (char*)d_ws;

    double* dsum = (double*)(ws + WS_DSUM);
    unsigned long long* nzc = (unsigned long long*)(ws + WS_NZC);
    double* KL = (double*)(ws + WS_KL);
    double* KK = (double*)(ws + WS_KK);
    float* sqv  = (float*)(ws + WS_SQ);
    float* csig = (float*)(ws + WS_CSIG);

    hipLaunchKernelGGL(k_rowsq, dim3(NN / 256), dim3(256), 0, stream, x, sqv, dsum, nzc);
    hipLaunchKernelGGL(k_d2, dim3(GRID_D2), dim3(256), 0, stream, x, sqv, out, dsum, nzc);
    hipLaunchKernelGGL(k_sigmas, dim3(1), dim3(128), 0, stream, dsum, nzc, csig, KL, KK);
    hipLaunchKernelGGL(k_sweep_coarse, dim3(GRID_SW), dim3(256), 0, stream, out, lk, csig, KL, KK);
    hipLaunchKernelGGL(k_sweep_refine, dim3(GRID_SW), dim3(256), 0, stream, out, lk, csig, KL, KK);
    hipLaunchKernelGGL(k_final, dim3(GRID_D2), dim3(256), 0, stream, out, KL, KK, csig);
}